// Round 1
// baseline (1476.382 us; speedup 1.0000x reference)
//
#include <hip/hip_runtime.h>
#include <math.h>

// Problem constants
constexpr int Bc  = 4;
constexpr int Sc  = 2048;
constexpr int Dc  = 512;
constexpr int Hc  = 8;
constexpr int DKc = 64;
constexpr int Mc  = Bc * Sc;   // 8192 rows

// ---------------------------------------------------------------------------
// GEMM: out = X[M,K] @ W[N,K]^T + bias   (M=8192, N=K=512)
// MODE 0: write flat [M,N]
// MODE 1: write head-scattered qh/kh/vh layout: [((b*H+h)*S+s)*DK + dk]
// 64x64 tile, 256 threads, 4x4 acc/thread, k-tile 32.
// LDS holds transposed tiles XsT[k][m], WsT[k][n] so the inner loop is
// outer-product: 2x ds_read_b128 + 16 v_fma per k. Pad 68 keeps 16B align
// and caps staging-store conflicts at 4-way.
// ---------------------------------------------------------------------------
template<int MODE>
__global__ __launch_bounds__(256)
void gemm_bt(const float* __restrict__ X, const float* __restrict__ W,
             const float* __restrict__ bias, float* __restrict__ out)
{
    constexpr int K = Dc;
    constexpr int N = Dc;
    __shared__ float Xs[32][68];
    __shared__ float Ws[32][68];

    const int t    = threadIdx.x;
    const int tx   = t & 15;   // n quad (0..15)
    const int ty   = t >> 4;   // m quad (0..15)
    const int row0 = blockIdx.x * 64;
    const int col0 = blockIdx.y * 64;

    float acc[4][4] = {};

    for (int k0 = 0; k0 < K; k0 += 32) {
        // global loads: 2 float4 per matrix per thread, 128B-contiguous per 8 lanes
        float4 xv[2], wv[2];
#pragma unroll
        for (int c = 0; c < 2; ++c) {
            int qi = t + c * 256;          // 0..511 float4 index
            int rr = qi >> 3;              // tile row 0..63
            int kv = (qi & 7) << 2;        // k offset 0..28
            xv[c] = *(const float4*)(X + (size_t)(row0 + rr) * K + k0 + kv);
            wv[c] = *(const float4*)(W + (size_t)(col0 + rr) * K + k0 + kv);
        }
        __syncthreads();
#pragma unroll
        for (int c = 0; c < 2; ++c) {
            int qi = t + c * 256;
            int rr = qi >> 3;
            int kv = (qi & 7) << 2;
            Xs[kv + 0][rr] = xv[c].x; Xs[kv + 1][rr] = xv[c].y;
            Xs[kv + 2][rr] = xv[c].z; Xs[kv + 3][rr] = xv[c].w;
            Ws[kv + 0][rr] = wv[c].x; Ws[kv + 1][rr] = wv[c].y;
            Ws[kv + 2][rr] = wv[c].z; Ws[kv + 3][rr] = wv[c].w;
        }
        __syncthreads();
#pragma unroll
        for (int kk = 0; kk < 32; ++kk) {
            float4 a4 = *(const float4*)&Xs[kk][ty * 4];
            float4 b4 = *(const float4*)&Ws[kk][tx * 4];
            float a[4] = {a4.x, a4.y, a4.z, a4.w};
            float b[4] = {b4.x, b4.y, b4.z, b4.w};
#pragma unroll
            for (int i = 0; i < 4; ++i)
#pragma unroll
                for (int j = 0; j < 4; ++j)
                    acc[i][j] += a[i] * b[j];
        }
    }

    const int j0 = col0 + tx * 4;
    float bz[4] = {bias[j0], bias[j0 + 1], bias[j0 + 2], bias[j0 + 3]};
#pragma unroll
    for (int i = 0; i < 4; ++i) {
        int n = row0 + ty * 4 + i;
        float4 r;
        r.x = acc[i][0] + bz[0];
        r.y = acc[i][1] + bz[1];
        r.z = acc[i][2] + bz[2];
        r.w = acc[i][3] + bz[3];
        if (MODE == 0) {
            *(float4*)(out + (size_t)n * N + j0) = r;
        } else {
            int b  = n >> 11;          // n / S
            int s  = n & (Sc - 1);     // n % S
            int h  = col0 >> 6;        // all 4 cols in same head (col0 mult of 64)
            int dk0 = tx * 4;
            *(float4*)(out + ((size_t)(b * Hc + h) * Sc + s) * DKc + dk0) = r;
        }
    }
}

// ---------------------------------------------------------------------------
// Flash-style attention, fp32. Grid: (S/64, B*H). Block: 128 threads.
// Thread pair (2r, 2r+1) owns q-row r of the 64-row Q tile; each lane holds
// one 32-dim half of q and of the output accumulator. Score dot is completed
// with __shfl_xor(.,1). Online softmax with running (m, l).
// scores = (q.k)/H  (the reference's /H quirk), mask==0 -> -1e9.
// ---------------------------------------------------------------------------
__global__ __launch_bounds__(128)
void attn_flash(const float* __restrict__ qh, const float* __restrict__ kh,
                const float* __restrict__ vh, const int* __restrict__ mask,
                float* __restrict__ ctx)
{
    __shared__ float Ks[32][64];
    __shared__ float Vs[32][64];

    const int bh = blockIdx.y;           // 0..31
    const int b  = bh >> 3;
    const int h  = bh & 7;
    const int q0 = blockIdx.x * 64;
    const int tid = threadIdx.x;
    const int r  = tid >> 1;             // q row in tile (0..63)
    const int hf = tid & 1;              // which 32-dim half

    const size_t headbase = (size_t)bh * Sc * DKc;

    // q half-row into registers
    float qreg[32];
    {
        const float* qp = qh + headbase + (size_t)(q0 + r) * DKc + hf * 32;
#pragma unroll
        for (int c = 0; c < 8; ++c) {
            float4 v4 = *(const float4*)(qp + 4 * c);
            qreg[4 * c + 0] = v4.x; qreg[4 * c + 1] = v4.y;
            qreg[4 * c + 2] = v4.z; qreg[4 * c + 3] = v4.w;
        }
    }

    float o[32];
#pragma unroll
    for (int i = 0; i < 32; ++i) o[i] = 0.f;
    float m = -INFINITY, l = 0.f;

    const int* mrow = mask + ((size_t)b * Sc + (q0 + r)) * Sc;

    for (int kt = 0; kt < Sc; kt += 32) {
        // stage K,V tiles (32x64 each)
        {
            const float* kp = kh + headbase + (size_t)kt * DKc;
            const float* vp = vh + headbase + (size_t)kt * DKc;
#pragma unroll
            for (int c = 0; c < 4; ++c) {
                int idx = tid + c * 128;       // 0..511 float4 index
                int jj  = idx >> 4;            // 0..31
                int dd  = (idx & 15) * 4;      // 0..60
                *(float4*)&Ks[jj][dd] = *(const float4*)(kp + jj * 64 + dd);
                *(float4*)&Vs[jj][dd] = *(const float4*)(vp + jj * 64 + dd);
            }
        }
        __syncthreads();

        // mask bits for this row's 32 keys (bit set = masked out)
        unsigned mb = 0u;
#pragma unroll
        for (int c = 0; c < 8; ++c) {
            int4 mi = *(const int4*)(mrow + kt + 4 * c);
            mb |= (mi.x == 0 ? 1u : 0u) << (4 * c + 0);
            mb |= (mi.y == 0 ? 1u : 0u) << (4 * c + 1);
            mb |= (mi.z == 0 ? 1u : 0u) << (4 * c + 2);
            mb |= (mi.w == 0 ? 1u : 0u) << (4 * c + 3);
        }

        // scores for 32 keys
        float sreg[32];
        float mt = -INFINITY;
#pragma unroll
        for (int j = 0; j < 32; ++j) {
            float p = 0.f;
#pragma unroll
            for (int c = 0; c < 8; ++c) {
                float4 kv = *(const float4*)&Ks[j][hf * 32 + 4 * c];
                p += qreg[4 * c + 0] * kv.x + qreg[4 * c + 1] * kv.y +
                     qreg[4 * c + 2] * kv.z + qreg[4 * c + 3] * kv.w;
            }
            p += __shfl_xor(p, 1);             // complete 64-dim dot across the pair
            float s = p * 0.125f;              // /H quirk
            s = ((mb >> j) & 1u) ? -1e9f : s;
            sreg[j] = s;
            mt = fmaxf(mt, s);
        }

        // online softmax update
        float mnew  = fmaxf(m, mt);
        float alpha = __expf(m - mnew);
        l *= alpha;
#pragma unroll
        for (int i = 0; i < 32; ++i) o[i] *= alpha;
#pragma unroll
        for (int j = 0; j < 32; ++j) {
            float p = __expf(sreg[j] - mnew);
            l += p;
#pragma unroll
            for (int c = 0; c < 8; ++c) {
                float4 vv = *(const float4*)&Vs[j][hf * 32 + 4 * c];
                o[4 * c + 0] += p * vv.x; o[4 * c + 1] += p * vv.y;
                o[4 * c + 2] += p * vv.z; o[4 * c + 3] += p * vv.w;
            }
        }
        m = mnew;
        __syncthreads();
    }

    // normalize + write ctx in flat [B,S,D] layout (d = h*64 + hf*32 + i)
    float inv = 1.f / l;
    float* op = ctx + ((size_t)b * Sc + (q0 + r)) * Dc + h * DKc + hf * 32;
#pragma unroll
    for (int c = 0; c < 8; ++c) {
        float4 v4;
        v4.x = o[4 * c + 0] * inv; v4.y = o[4 * c + 1] * inv;
        v4.z = o[4 * c + 2] * inv; v4.w = o[4 * c + 3] * inv;
        *(float4*)(op + 4 * c) = v4;
    }
}

// ---------------------------------------------------------------------------
extern "C" void kernel_launch(void* const* d_in, const int* in_sizes, int n_in,
                              void* d_out, int out_size, void* d_ws, size_t ws_size,
                              hipStream_t stream)
{
    (void)in_sizes; (void)n_in; (void)out_size; (void)ws_size;

    const float* q    = (const float*)d_in[0];
    const float* k    = (const float*)d_in[1];
    const float* v    = (const float*)d_in[2];
    const int*   mask = (const int*)  d_in[3];
    const float* Wq   = (const float*)d_in[4];
    const float* bq   = (const float*)d_in[5];
    const float* Wk   = (const float*)d_in[6];
    const float* bk   = (const float*)d_in[7];
    const float* Wv   = (const float*)d_in[8];
    const float* bv   = (const float*)d_in[9];
    const float* Wo   = (const float*)d_in[10];
    const float* bo   = (const float*)d_in[11];
    float* out = (float*)d_out;

    // workspace layout (fp32): qh | kh | vh  in [B,H,S,DK], ctx in [B,S,D]
    constexpr size_t TEN = (size_t)Bc * Hc * Sc * DKc;   // 4,194,304 elems
    float* qh  = (float*)d_ws;
    float* kh  = qh + TEN;
    float* vh  = kh + TEN;
    float* ctx = vh + TEN;

    dim3 gg(Mc / 64, Dc / 64);   // (128, 8)
    dim3 bb(256);

    gemm_bt<1><<<gg, bb, 0, stream>>>(q, Wq, bq, qh);
    gemm_bt<1><<<gg, bb, 0, stream>>>(k, Wk, bk, kh);
    gemm_bt<1><<<gg, bb, 0, stream>>>(v, Wv, bv, vh);

    attn_flash<<<dim3(Sc / 64, Bc * Hc), 128, 0, stream>>>(qh, kh, vh, mask, ctx);

    gemm_bt<0><<<gg, bb, 0, stream>>>(ctx, Wo, bo, out);
}

// Round 2
// 594.429 us; speedup vs baseline: 2.4837x; 2.4837x over previous
//
#include <hip/hip_runtime.h>
#include <math.h>

// Problem constants
constexpr int Bc  = 4;
constexpr int Sc  = 2048;
constexpr int Dc  = 512;
constexpr int Hc  = 8;
constexpr int DKc = 64;
constexpr int Mc  = Bc * Sc;   // 8192 rows

typedef __attribute__((ext_vector_type(8))) short s16x8;   // 8 bf16 (4 VGPRs) MFMA frag
typedef __attribute__((ext_vector_type(4))) float f32x4;   // MFMA accumulator

__device__ __forceinline__ unsigned short f2bf(float f) {
    __bf16 h = (__bf16)f;                 // RNE convert
    return __builtin_bit_cast(unsigned short, h);
}

// ---------------------------------------------------------------------------
// mask [B,1,S,S] int32 -> keep-bit words: bit j of word w == (mask[w*64+j]!=0)
// one wave produces one 64-bit word via ballot; coalesced 256B reads.
// ---------------------------------------------------------------------------
__global__ __launch_bounds__(256)
void pack_mask(const int* __restrict__ mask, unsigned long long* __restrict__ out,
               int nwords)
{
    int gw   = (blockIdx.x * blockDim.x + threadIdx.x) >> 6;
    int lane = threadIdx.x & 63;
    int nw   = (gridDim.x * blockDim.x) >> 6;
    for (int w = gw; w < nwords; w += nw) {
        int v = mask[(size_t)w * 64 + lane];
        unsigned long long bits = __ballot(v != 0);
        if (lane == 0) out[w] = bits;
    }
}

// ---------------------------------------------------------------------------
// GEMM: out = (X[M,K] @ W[N,K]^T + bias) * scale   (M=8192, N=K=512), fp32 core.
// MODE 0: fp32 flat [M,N]
// MODE 1: bf16 head layout   [((b*H+h)*S+s)*DK + dk]      (Q: scale=1/8, K)
// MODE 2: bf16 head TRANSPOSED [((b*H+h)*DK+dk)*S + s]    (V)
// ---------------------------------------------------------------------------
template<int MODE>
__global__ __launch_bounds__(256)
void gemm_bt(const float* __restrict__ X, const float* __restrict__ W,
             const float* __restrict__ bias, void* __restrict__ outv, float scale)
{
    constexpr int K = Dc;
    constexpr int N = Dc;
    __shared__ float Xs[32][68];
    __shared__ float Ws[32][68];

    const int t    = threadIdx.x;
    const int tx   = t & 15;   // n quad
    const int ty   = t >> 4;   // m quad
    const int row0 = blockIdx.x * 64;
    const int col0 = blockIdx.y * 64;

    float acc[4][4] = {};

    for (int k0 = 0; k0 < K; k0 += 32) {
        float4 xv[2], wv[2];
#pragma unroll
        for (int c = 0; c < 2; ++c) {
            int qi = t + c * 256;
            int rr = qi >> 3;
            int kv = (qi & 7) << 2;
            xv[c] = *(const float4*)(X + (size_t)(row0 + rr) * K + k0 + kv);
            wv[c] = *(const float4*)(W + (size_t)(col0 + rr) * K + k0 + kv);
        }
        __syncthreads();
#pragma unroll
        for (int c = 0; c < 2; ++c) {
            int qi = t + c * 256;
            int rr = qi >> 3;
            int kv = (qi & 7) << 2;
            Xs[kv + 0][rr] = xv[c].x; Xs[kv + 1][rr] = xv[c].y;
            Xs[kv + 2][rr] = xv[c].z; Xs[kv + 3][rr] = xv[c].w;
            Ws[kv + 0][rr] = wv[c].x; Ws[kv + 1][rr] = wv[c].y;
            Ws[kv + 2][rr] = wv[c].z; Ws[kv + 3][rr] = wv[c].w;
        }
        __syncthreads();
#pragma unroll
        for (int kk = 0; kk < 32; ++kk) {
            float4 a4 = *(const float4*)&Xs[kk][ty * 4];
            float4 b4 = *(const float4*)&Ws[kk][tx * 4];
            float a[4] = {a4.x, a4.y, a4.z, a4.w};
            float b[4] = {b4.x, b4.y, b4.z, b4.w};
#pragma unroll
            for (int i = 0; i < 4; ++i)
#pragma unroll
                for (int j = 0; j < 4; ++j)
                    acc[i][j] += a[i] * b[j];
        }
    }

    const int j0 = col0 + tx * 4;
    float bz[4] = {bias[j0], bias[j0 + 1], bias[j0 + 2], bias[j0 + 3]};

    if (MODE == 0) {
        float* out = (float*)outv;
#pragma unroll
        for (int i = 0; i < 4; ++i) {
            int n = row0 + ty * 4 + i;
            float4 r;
            r.x = acc[i][0] + bz[0]; r.y = acc[i][1] + bz[1];
            r.z = acc[i][2] + bz[2]; r.w = acc[i][3] + bz[3];
            *(float4*)(out + (size_t)n * N + j0) = r;
        }
    } else if (MODE == 1) {
        unsigned short* ob = (unsigned short*)outv;
        const int h = col0 >> 6;
#pragma unroll
        for (int i = 0; i < 4; ++i) {
            int n = row0 + ty * 4 + i;
            int b = n >> 11, s = n & (Sc - 1);
            ushort4 pk;
            pk.x = f2bf((acc[i][0] + bz[0]) * scale);
            pk.y = f2bf((acc[i][1] + bz[1]) * scale);
            pk.z = f2bf((acc[i][2] + bz[2]) * scale);
            pk.w = f2bf((acc[i][3] + bz[3]) * scale);
            *(ushort4*)(ob + ((size_t)(b * Hc + h) * Sc + s) * DKc + tx * 4) = pk;
        }
    } else {
        unsigned short* ob = (unsigned short*)outv;
        const int h  = col0 >> 6;
        const int b  = row0 >> 11;
        const int s0 = (row0 & (Sc - 1)) + ty * 4;
#pragma unroll
        for (int j = 0; j < 4; ++j) {
            int dk = tx * 4 + j;
            ushort4 pk;
            pk.x = f2bf((acc[0][j] + bz[j]) * scale);
            pk.y = f2bf((acc[1][j] + bz[j]) * scale);
            pk.z = f2bf((acc[2][j] + bz[j]) * scale);
            pk.w = f2bf((acc[3][j] + bz[j]) * scale);
            *(ushort4*)(ob + ((size_t)(b * Hc + h) * DKc + dk) * Sc + s0) = pk;
        }
    }
}

// ---------------------------------------------------------------------------
// bf16 MFMA flash attention. Grid (S/64, B*H), block 256 = 4 waves.
// Wave w owns q rows [q0+16w, q0+16w+16). Per 64-key KV tile:
//   S^T[key][q] = K·Q^T via mfma(A=K,B=Q)  -> C layout key=(qd*4+reg), q=ln
//   online softmax (q=ln lanes; key reduce = xor16/xor32 shuffles)
//   P packed bf16 -> LDS rows [q][key] (8B write), read back as B-frag (b128)
//   ctx^T[dv][q] += V_t·P^T via mfma(A=Vt,B=P)  -> alpha-rescale is lane-local
// LDS rows padded to 72 shorts (144B): b128 frag reads are 2-way/free.
// qh is pre-scaled by 1/8 (the reference's /H quirk).
// ---------------------------------------------------------------------------
__global__ __launch_bounds__(256)
void attn_mfma(const unsigned short* __restrict__ qh, const unsigned short* __restrict__ kh,
               const unsigned short* __restrict__ vt, const unsigned long long* __restrict__ mbits,
               float* __restrict__ ctx)
{
    __shared__ unsigned short Ks[64][72];      // [key][d]
    __shared__ unsigned short Vs[64][72];      // [dv][key]
    __shared__ unsigned short Ps[4][16][72];   // per-wave [q][key]

    const int bh = blockIdx.y, b = bh >> 3, h = bh & 7;
    const int q0 = blockIdx.x * 64;
    const int tid = threadIdx.x;
    const int w = tid >> 6, lane = tid & 63, ln = lane & 15, qd = lane >> 4;

    const int qrow = q0 + w * 16 + ln;

    // Q B-frags (q=ln, d = qd*8.. / +32), resident whole kernel
    s16x8 qf0, qf1;
    {
        const unsigned short* qp = qh + ((size_t)bh * Sc + qrow) * DKc + qd * 8;
        qf0 = *(const s16x8*)(qp);
        qf1 = *(const s16x8*)(qp + 32);
    }

    f32x4 ctxf[4];
#pragma unroll
    for (int m = 0; m < 4; ++m) ctxf[m] = f32x4{0.f, 0.f, 0.f, 0.f};
    float mrun = -INFINITY, lrun = 0.f;

    const unsigned long long* mrow = mbits + ((size_t)b * Sc + qrow) * (Sc / 64);
    const unsigned short* kbase = kh + (size_t)bh * Sc * DKc;
    const unsigned short* vbase = vt + (size_t)bh * DKc * Sc;

    for (int kt = 0; kt < Sc; kt += 64) {
        // prefetch staging data to registers (overlaps barrier wait)
        uint4 kv[2], vv[2];
#pragma unroll
        for (int c = 0; c < 2; ++c) {
            int idx = tid + c * 256;
            int r = idx >> 3, cc = idx & 7;
            kv[c] = *(const uint4*)(kbase + (size_t)(kt + r) * DKc + cc * 8);
            vv[c] = *(const uint4*)(vbase + (size_t)r * Sc + kt + cc * 8);
        }
        const unsigned long long mw = mrow[kt >> 6];

        __syncthreads();
#pragma unroll
        for (int c = 0; c < 2; ++c) {
            int idx = tid + c * 256;
            int r = idx >> 3, cc = idx & 7;
            *(uint4*)&Ks[r][cc * 8] = kv[c];
            *(uint4*)&Vs[r][cc * 8] = vv[c];
        }
        __syncthreads();

        // ---- S^T = K · Q^T : 4 key-tiles x 2 d-halves
        f32x4 sf[4];
#pragma unroll
        for (int m = 0; m < 4; ++m) {
            s16x8 k0 = *(const s16x8*)&Ks[m * 16 + ln][qd * 8];
            s16x8 k1 = *(const s16x8*)&Ks[m * 16 + ln][32 + qd * 8];
            f32x4 z = f32x4{0.f, 0.f, 0.f, 0.f};
            z = __builtin_amdgcn_mfma_f32_16x16x32_bf16(k0, qf0, z, 0, 0, 0);
            z = __builtin_amdgcn_mfma_f32_16x16x32_bf16(k1, qf1, z, 0, 0, 0);
            sf[m] = z;
        }

        // ---- mask + online softmax (key = m*16 + qd*4 + r, q = ln)
        float sc[4][4];
        float mt = -INFINITY;
#pragma unroll
        for (int m = 0; m < 4; ++m)
#pragma unroll
            for (int r = 0; r < 4; ++r) {
                int kb = m * 16 + qd * 4 + r;
                float s = ((mw >> kb) & 1ull) ? sf[m][r] : -1e9f;
                sc[m][r] = s;
                mt = fmaxf(mt, s);
            }
        mt = fmaxf(mt, __shfl_xor(mt, 16));
        mt = fmaxf(mt, __shfl_xor(mt, 32));
        const float mnew  = fmaxf(mrun, mt);
        const float alpha = __expf(mrun - mnew);
        mrun = mnew;
        lrun *= alpha;

#pragma unroll
        for (int m = 0; m < 4; ++m) {
            float p0 = __expf(sc[m][0] - mnew);
            float p1 = __expf(sc[m][1] - mnew);
            float p2 = __expf(sc[m][2] - mnew);
            float p3 = __expf(sc[m][3] - mnew);
            lrun += p0 + p1 + p2 + p3;
            ushort4 pk;
            pk.x = f2bf(p0); pk.y = f2bf(p1); pk.z = f2bf(p2); pk.w = f2bf(p3);
            *(ushort4*)&Ps[w][ln][m * 16 + qd * 4] = pk;   // P[q][key], 4 keys
        }
#pragma unroll
        for (int m = 0; m < 4; ++m) {
            ctxf[m][0] *= alpha; ctxf[m][1] *= alpha;
            ctxf[m][2] *= alpha; ctxf[m][3] *= alpha;
        }

        // ---- ctx^T += V_t · P^T : 4 dv-tiles x 2 key-halves
        s16x8 pf0 = *(const s16x8*)&Ps[w][ln][qd * 8];
        s16x8 pf1 = *(const s16x8*)&Ps[w][ln][32 + qd * 8];
#pragma unroll
        for (int m = 0; m < 4; ++m) {
            s16x8 v0 = *(const s16x8*)&Vs[m * 16 + ln][qd * 8];
            s16x8 v1 = *(const s16x8*)&Vs[m * 16 + ln][32 + qd * 8];
            ctxf[m] = __builtin_amdgcn_mfma_f32_16x16x32_bf16(v0, pf0, ctxf[m], 0, 0, 0);
            ctxf[m] = __builtin_amdgcn_mfma_f32_16x16x32_bf16(v1, pf1, ctxf[m], 0, 0, 0);
        }
    }

    // final reduce of l over qd groups, normalize, write ctx fp32 [B,S,D]
    lrun += __shfl_xor(lrun, 16);
    lrun += __shfl_xor(lrun, 32);
    const float inv = 1.f / lrun;

    float* op = ctx + ((size_t)(b * Sc + qrow)) * Dc + h * DKc;
#pragma unroll
    for (int m = 0; m < 4; ++m) {
        float4 st;
        st.x = ctxf[m][0] * inv; st.y = ctxf[m][1] * inv;
        st.z = ctxf[m][2] * inv; st.w = ctxf[m][3] * inv;
        *(float4*)(op + m * 16 + qd * 4) = st;   // dv = m*16 + qd*4 + r
    }
}

// ---------------------------------------------------------------------------
extern "C" void kernel_launch(void* const* d_in, const int* in_sizes, int n_in,
                              void* d_out, int out_size, void* d_ws, size_t ws_size,
                              hipStream_t stream)
{
    (void)in_sizes; (void)n_in; (void)out_size; (void)ws_size;

    const float* q    = (const float*)d_in[0];
    const float* k    = (const float*)d_in[1];
    const float* v    = (const float*)d_in[2];
    const int*   mask = (const int*)  d_in[3];
    const float* Wq   = (const float*)d_in[4];
    const float* bq   = (const float*)d_in[5];
    const float* Wk   = (const float*)d_in[6];
    const float* bk   = (const float*)d_in[7];
    const float* Wv   = (const float*)d_in[8];
    const float* bv   = (const float*)d_in[9];
    const float* Wo   = (const float*)d_in[10];
    const float* bo   = (const float*)d_in[11];
    float* out = (float*)d_out;

    // workspace carve
    constexpr size_t TEN = (size_t)Bc * Hc * Sc * DKc;       // 4,194,304 elems
    char* p = (char*)d_ws;
    float*              ctx   = (float*)p;            p += TEN * Hc * 0 + (size_t)Mc * Dc * 4;  // 16 MB
    unsigned short*     qh_bf = (unsigned short*)p;   p += TEN * 2;   // 8 MB
    unsigned short*     kh_bf = (unsigned short*)p;   p += TEN * 2;   // 8 MB
    unsigned short*     vh_t  = (unsigned short*)p;   p += TEN * 2;   // 8 MB
    unsigned long long* mbits = (unsigned long long*)p;               // 2 MB

    const int nwords = Bc * Sc * (Sc / 64);   // 262144

    dim3 gg(Mc / 64, Dc / 64);   // (128, 8)
    dim3 bb(256);

    pack_mask<<<dim3(512), bb, 0, stream>>>(mask, mbits, nwords);
    gemm_bt<1><<<gg, bb, 0, stream>>>(q, Wq, bq, qh_bf, 0.125f);  // fold /H into Q
    gemm_bt<1><<<gg, bb, 0, stream>>>(k, Wk, bk, kh_bf, 1.0f);
    gemm_bt<2><<<gg, bb, 0, stream>>>(v, Wv, bv, vh_t, 1.0f);     // transposed head layout
    attn_mfma<<<dim3(Sc / 64, Bc * Hc), bb, 0, stream>>>(qh_bf, kh_bf, vh_t, mbits, ctx);
    gemm_bt<0><<<gg, bb, 0, stream>>>(ctx, Wo, bo, out, 1.0f);
}

// Round 3
// 449.566 us; speedup vs baseline: 3.2840x; 1.3222x over previous
//
#include <hip/hip_runtime.h>
#include <math.h>

// Problem constants
constexpr int Bc  = 4;
constexpr int Sc  = 2048;
constexpr int Dc  = 512;
constexpr int Hc  = 8;
constexpr int DKc = 64;
constexpr int Mc  = Bc * Sc;   // 8192 rows

typedef __attribute__((ext_vector_type(8)))  short s16x8;   // 8 bf16 MFMA frag
typedef __attribute__((ext_vector_type(4)))  float f32x4;   // 16x16 accumulator
typedef __attribute__((ext_vector_type(16))) float f32x16;  // 32x32 accumulator

__device__ __forceinline__ unsigned short f2bf(float f) {
    __bf16 h = (__bf16)f;                 // RNE convert
    return __builtin_bit_cast(unsigned short, h);
}

__device__ __forceinline__ uint4 pack8(float4 a, float4 b) {
    uint4 u;
    u.x = (unsigned)f2bf(a.x) | ((unsigned)f2bf(a.y) << 16);
    u.y = (unsigned)f2bf(a.z) | ((unsigned)f2bf(a.w) << 16);
    u.z = (unsigned)f2bf(b.x) | ((unsigned)f2bf(b.y) << 16);
    u.w = (unsigned)f2bf(b.z) | ((unsigned)f2bf(b.w) << 16);
    return u;
}

// ---------------------------------------------------------------------------
// mask [B,1,S,S] int32 -> keep-bit words: bit j of word w == (mask[w*64+j]!=0)
// ---------------------------------------------------------------------------
__global__ __launch_bounds__(256)
void pack_mask(const int* __restrict__ mask, unsigned long long* __restrict__ out,
               int nwords)
{
    int gw   = (blockIdx.x * blockDim.x + threadIdx.x) >> 6;
    int lane = threadIdx.x & 63;
    int nw   = (gridDim.x * blockDim.x) >> 6;
    for (int w = gw; w < nwords; w += nw) {
        int v = mask[(size_t)w * 64 + lane];
        unsigned long long bits = __ballot(v != 0);
        if (lane == 0) out[w] = bits;
    }
}

// ---------------------------------------------------------------------------
// bf16-MFMA GEMM: out = (X[M,512] @ W[512,512]^T + bias) * scale
// fp32 X/W are converted to bf16 inside the LDS staging path (XBF=false);
// XBF=true reads a bf16 X (ctx) directly.
// Tile 128m x 64n, 256 threads = 4 waves (2x2), wave = 64m x 32n of 16x16x32.
// Grid (64, 8) = 512 blocks -> 2 blocks/CU.
// MODE 0: fp32 flat [M,512]
// MODE 1: bf16 head layout   [((b*H+h)*S+s)*64 + dk]   (Q: scale=1/8, K)
// MODE 2: bf16 head transposed [((b*H+h)*64+dk)*S + s] (V)
// LDS rows padded to 72 shorts: frag b128 reads sit at the 8-lane/quad floor.
// ---------------------------------------------------------------------------
template<int MODE, bool XBF>
__global__ __launch_bounds__(256, 2)
void gemm_mfma(const void* __restrict__ Xv, const float* __restrict__ Wf,
               const float* __restrict__ bias, void* __restrict__ outv, float scale)
{
    __shared__ unsigned short Xs[128][72];
    __shared__ unsigned short Ws[64][72];

    const int tid = threadIdx.x;
    const int w = tid >> 6, lane = tid & 63, ln = lane & 15, qd = lane >> 4;
    const int wm = (w >> 1) * 64, wn = (w & 1) * 32;
    const int row0 = blockIdx.x * 128, col0 = blockIdx.y * 64;

    f32x4 acc[4][2];
#pragma unroll
    for (int mt = 0; mt < 4; ++mt)
#pragma unroll
        for (int nt = 0; nt < 2; ++nt) acc[mt][nt] = f32x4{0.f, 0.f, 0.f, 0.f};

    for (int k0 = 0; k0 < 512; k0 += 64) {
        uint4 xs[4], ws[2];
#pragma unroll
        for (int c = 0; c < 4; ++c) {
            int idx = tid + c * 256, r = idx >> 3, cc = idx & 7;
            if (XBF) {
                xs[c] = *(const uint4*)((const unsigned short*)Xv +
                                        (size_t)(row0 + r) * 512 + k0 + cc * 8);
            } else {
                const float* xp = (const float*)Xv + (size_t)(row0 + r) * 512 + k0 + cc * 8;
                xs[c] = pack8(*(const float4*)xp, *(const float4*)(xp + 4));
            }
        }
#pragma unroll
        for (int c = 0; c < 2; ++c) {
            int idx = tid + c * 256, r = idx >> 3, cc = idx & 7;
            const float* wp = Wf + (size_t)(col0 + r) * 512 + k0 + cc * 8;
            ws[c] = pack8(*(const float4*)wp, *(const float4*)(wp + 4));
        }
        __syncthreads();
#pragma unroll
        for (int c = 0; c < 4; ++c) {
            int idx = tid + c * 256, r = idx >> 3, cc = idx & 7;
            *(uint4*)&Xs[r][cc * 8] = xs[c];
        }
#pragma unroll
        for (int c = 0; c < 2; ++c) {
            int idx = tid + c * 256, r = idx >> 3, cc = idx & 7;
            *(uint4*)&Ws[r][cc * 8] = ws[c];
        }
        __syncthreads();
#pragma unroll
        for (int kc = 0; kc < 2; ++kc) {
            s16x8 af[4], bfr[2];
#pragma unroll
            for (int mt = 0; mt < 4; ++mt)
                af[mt] = *(const s16x8*)&Xs[wm + mt * 16 + ln][kc * 32 + qd * 8];
#pragma unroll
            for (int nt = 0; nt < 2; ++nt)
                bfr[nt] = *(const s16x8*)&Ws[wn + nt * 16 + ln][kc * 32 + qd * 8];
#pragma unroll
            for (int mt = 0; mt < 4; ++mt)
#pragma unroll
                for (int nt = 0; nt < 2; ++nt)
                    acc[mt][nt] = __builtin_amdgcn_mfma_f32_16x16x32_bf16(
                        af[mt], bfr[nt], acc[mt][nt], 0, 0, 0);
        }
    }

    // epilogue: C layout m = mbase + r (r=reg), n = col0+wn+nt*16+ln
#pragma unroll
    for (int nt = 0; nt < 2; ++nt) {
        const int n = col0 + wn + nt * 16 + ln;
        const float bz = bias[n];
#pragma unroll
        for (int mt = 0; mt < 4; ++mt) {
            const int mbase = row0 + wm + mt * 16 + qd * 4;
            if (MODE == 0) {
                float* o = (float*)outv;
#pragma unroll
                for (int r = 0; r < 4; ++r)
                    o[(size_t)(mbase + r) * 512 + n] = acc[mt][nt][r] + bz;
            } else if (MODE == 1) {
                unsigned short* o = (unsigned short*)outv;
                const int h = n >> 6, dk = n & 63;
#pragma unroll
                for (int r = 0; r < 4; ++r) {
                    int m = mbase + r, b = m >> 11, s = m & 2047;
                    o[((size_t)(b * Hc + h) * Sc + s) * 64 + dk] =
                        f2bf((acc[mt][nt][r] + bz) * scale);
                }
            } else {
                unsigned short* o = (unsigned short*)outv;
                const int h = n >> 6, dk = n & 63;
                const int b = mbase >> 11, s = mbase & 2047;
                ushort4 pk;
                pk.x = f2bf((acc[mt][nt][0] + bz) * scale);
                pk.y = f2bf((acc[mt][nt][1] + bz) * scale);
                pk.z = f2bf((acc[mt][nt][2] + bz) * scale);
                pk.w = f2bf((acc[mt][nt][3] + bz) * scale);
                *(ushort4*)(o + ((size_t)(b * Hc + h) * 64 + dk) * Sc + s) = pk;
            }
        }
    }
}

// ---------------------------------------------------------------------------
// bf16 32x32x16-MFMA flash attention. Grid (S/128, B*H), 256 thr = 4 waves.
// Wave w owns 32 q rows (q = q0 + 32w + ln). Per 64-key tile:
//   S^T[key][q] = K·Q^T : 2 key-subtiles x 4 K-chunks (8 MFMA, Q resident)
//   online softmax: per-lane 32 keys of ONE q; key-reduce = xor32 only
//   P -> LDS [q][key] (b64 writes at 4-cyc floor), read back as B-frags
//   ctx^T[dv][q] += V_t·P^T : 2 dv-subtiles x 4 chunks (8 MFMA)
// C/D: col(q)=lane&31, row=(reg&3)+8*(reg>>2)+4*(lane>>5)  [m74/m101]
// A/B: m|n = lane&31, k = (lane>>5)*8 + j  (gfx950 K-doubling, round-2-style)
// __launch_bounds__(256,2): no spills (round-2's 64-VGPR cap wrote 355MB scratch)
// ---------------------------------------------------------------------------
__global__ __launch_bounds__(256, 2)
void attn_mfma(const unsigned short* __restrict__ qh, const unsigned short* __restrict__ kh,
               const unsigned short* __restrict__ vt, const unsigned long long* __restrict__ mbits,
               unsigned short* __restrict__ ctx)
{
    __shared__ unsigned short Ks[64][72];      // [key][d]
    __shared__ unsigned short Vs[64][72];      // [dv][key]
    __shared__ unsigned short Ps[4][32][72];   // per-wave [q][key]

    const int bh = blockIdx.y, b = bh >> 3, h = bh & 7;
    const int q0 = blockIdx.x * 128;
    const int tid = threadIdx.x;
    const int w = tid >> 6, lane = tid & 63, ln = lane & 31, hf = lane >> 5;
    const int qrow = q0 + w * 32 + ln;

    // Q B-frags, resident: Q[qrow][kc*16 + hf*8 + j]
    s16x8 qf[4];
    {
        const unsigned short* qp = qh + ((size_t)bh * Sc + qrow) * 64 + hf * 8;
#pragma unroll
        for (int kc = 0; kc < 4; ++kc) qf[kc] = *(const s16x8*)(qp + kc * 16);
    }

    f32x16 o0, o1;
#pragma unroll
    for (int r = 0; r < 16; ++r) { o0[r] = 0.f; o1[r] = 0.f; }
    float mrun = -INFINITY, lrun = 0.f;

    const unsigned long long* mrow = mbits + ((size_t)b * Sc + qrow) * (Sc / 64);
    const unsigned short* kbase = kh + (size_t)bh * Sc * 64;
    const unsigned short* vbase = vt + (size_t)bh * 64 * Sc;

    for (int kt = 0; kt < Sc; kt += 64) {
        uint4 kp[2], vp[2];
#pragma unroll
        for (int c = 0; c < 2; ++c) {
            int idx = tid + c * 256, r = idx >> 3, cc = idx & 7;
            kp[c] = *(const uint4*)(kbase + (size_t)(kt + r) * 64 + cc * 8);
            vp[c] = *(const uint4*)(vbase + (size_t)r * Sc + kt + cc * 8);
        }
        const unsigned long long mw = mrow[kt >> 6];

        __syncthreads();
#pragma unroll
        for (int c = 0; c < 2; ++c) {
            int idx = tid + c * 256, r = idx >> 3, cc = idx & 7;
            *(uint4*)&Ks[r][cc * 8] = kp[c];
            *(uint4*)&Vs[r][cc * 8] = vp[c];
        }
        __syncthreads();

        // ---- S^T = K · Q^T
        f32x16 s0, s1;
#pragma unroll
        for (int r = 0; r < 16; ++r) { s0[r] = 0.f; s1[r] = 0.f; }
#pragma unroll
        for (int kc = 0; kc < 4; ++kc) {
            s16x8 kf0 = *(const s16x8*)&Ks[ln]     [kc * 16 + hf * 8];
            s16x8 kf1 = *(const s16x8*)&Ks[32 + ln][kc * 16 + hf * 8];
            s0 = __builtin_amdgcn_mfma_f32_32x32x16_bf16(kf0, qf[kc], s0, 0, 0, 0);
            s1 = __builtin_amdgcn_mfma_f32_32x32x16_bf16(kf1, qf[kc], s1, 0, 0, 0);
        }

        // ---- mask + online softmax (this lane: q = qrow, 32 keys)
        float mt = -INFINITY;
#pragma unroll
        for (int r = 0; r < 16; ++r) {
            int key = (r & 3) + 8 * (r >> 2) + 4 * hf;
            s0[r] = ((mw >> key)        & 1ull) ? s0[r] : -1e9f;
            s1[r] = ((mw >> (32 + key)) & 1ull) ? s1[r] : -1e9f;
            mt = fmaxf(mt, fmaxf(s0[r], s1[r]));
        }
        mt = fmaxf(mt, __shfl_xor(mt, 32));
        const float mnew  = fmaxf(mrun, mt);
        const float alpha = __expf(mrun - mnew);
        mrun = mnew;
        lrun *= alpha;

        float psum = 0.f;
#pragma unroll
        for (int g = 0; g < 4; ++g) {
            float p0 = __expf(s0[g * 4 + 0] - mnew), p1 = __expf(s0[g * 4 + 1] - mnew);
            float p2 = __expf(s0[g * 4 + 2] - mnew), p3 = __expf(s0[g * 4 + 3] - mnew);
            float r0 = __expf(s1[g * 4 + 0] - mnew), r1 = __expf(s1[g * 4 + 1] - mnew);
            float r2 = __expf(s1[g * 4 + 2] - mnew), r3 = __expf(s1[g * 4 + 3] - mnew);
            psum += (p0 + p1 + p2 + p3) + (r0 + r1 + r2 + r3);
            ushort4 pa, pb;
            pa.x = f2bf(p0); pa.y = f2bf(p1); pa.z = f2bf(p2); pa.w = f2bf(p3);
            pb.x = f2bf(r0); pb.y = f2bf(r1); pb.z = f2bf(r2); pb.w = f2bf(r3);
            *(ushort4*)&Ps[w][ln][8 * g + 4 * hf]      = pa;
            *(ushort4*)&Ps[w][ln][32 + 8 * g + 4 * hf] = pb;
        }
        lrun += psum;
#pragma unroll
        for (int r = 0; r < 16; ++r) { o0[r] *= alpha; o1[r] *= alpha; }

        // ---- ctx^T += V_t · P^T   (Ps is per-wave: no barrier needed)
#pragma unroll
        for (int kc = 0; kc < 4; ++kc) {
            s16x8 pf  = *(const s16x8*)&Ps[w][ln][kc * 16 + hf * 8];
            s16x8 vf0 = *(const s16x8*)&Vs[ln]     [kc * 16 + hf * 8];
            s16x8 vf1 = *(const s16x8*)&Vs[32 + ln][kc * 16 + hf * 8];
            o0 = __builtin_amdgcn_mfma_f32_32x32x16_bf16(vf0, pf, o0, 0, 0, 0);
            o1 = __builtin_amdgcn_mfma_f32_32x32x16_bf16(vf1, pf, o1, 0, 0, 0);
        }
    }

    lrun += __shfl_xor(lrun, 32);
    const float inv = 1.f / lrun;

    // ctx bf16 [B,S,D]; lane's q = qrow, dv = sub*32 + 8g + 4hf + i
    unsigned short* op = ctx + ((size_t)(b * Sc + qrow)) * 512 + h * 64;
#pragma unroll
    for (int g = 0; g < 4; ++g) {
        ushort4 a, c2;
        a.x  = f2bf(o0[g * 4 + 0] * inv); a.y  = f2bf(o0[g * 4 + 1] * inv);
        a.z  = f2bf(o0[g * 4 + 2] * inv); a.w  = f2bf(o0[g * 4 + 3] * inv);
        c2.x = f2bf(o1[g * 4 + 0] * inv); c2.y = f2bf(o1[g * 4 + 1] * inv);
        c2.z = f2bf(o1[g * 4 + 2] * inv); c2.w = f2bf(o1[g * 4 + 3] * inv);
        *(ushort4*)(op + 8 * g + 4 * hf)      = a;
        *(ushort4*)(op + 32 + 8 * g + 4 * hf) = c2;
    }
}

// ---------------------------------------------------------------------------
extern "C" void kernel_launch(void* const* d_in, const int* in_sizes, int n_in,
                              void* d_out, int out_size, void* d_ws, size_t ws_size,
                              hipStream_t stream)
{
    (void)in_sizes; (void)n_in; (void)out_size; (void)ws_size;

    const float* q    = (const float*)d_in[0];
    const float* k    = (const float*)d_in[1];
    const float* v    = (const float*)d_in[2];
    const int*   mask = (const int*)  d_in[3];
    const float* Wq   = (const float*)d_in[4];
    const float* bq   = (const float*)d_in[5];
    const float* Wk   = (const float*)d_in[6];
    const float* bk   = (const float*)d_in[7];
    const float* Wv   = (const float*)d_in[8];
    const float* bv   = (const float*)d_in[9];
    const float* Wo   = (const float*)d_in[10];
    const float* bo   = (const float*)d_in[11];
    float* out = (float*)d_out;

    // workspace carve (all bf16 intermediates)
    constexpr size_t TEN = (size_t)Bc * Hc * Sc * DKc;   // 4,194,304 elems
    char* p = (char*)d_ws;
    unsigned short*     qh_bf = (unsigned short*)p;  p += TEN * 2;   // 8 MB
    unsigned short*     kh_bf = (unsigned short*)p;  p += TEN * 2;   // 8 MB
    unsigned short*     vt_bf = (unsigned short*)p;  p += TEN * 2;   // 8 MB
    unsigned short*     ctx   = (unsigned short*)p;  p += TEN * 2;   // 8 MB
    unsigned long long* mbits = (unsigned long long*)p;              // 2 MB

    const int nwords = Bc * Sc * (Sc / 64);   // 262144

    dim3 gg(Mc / 128, Dc / 64);   // (64, 8)
    dim3 bb(256);

    pack_mask<<<dim3(512), bb, 0, stream>>>(mask, mbits, nwords);
    gemm_mfma<1, false><<<gg, bb, 0, stream>>>(q, Wq, bq, qh_bf, 0.125f); // /H folded
    gemm_mfma<1, false><<<gg, bb, 0, stream>>>(k, Wk, bk, kh_bf, 1.0f);
    gemm_mfma<2, false><<<gg, bb, 0, stream>>>(v, Wv, bv, vt_bf, 1.0f);
    attn_mfma<<<dim3(Sc / 128, Bc * Hc), bb, 0, stream>>>(qh_bf, kh_bf, vt_bf, mbits, ctx);
    gemm_mfma<0, true><<<gg, bb, 0, stream>>>(ctx, Wo, bo, out, 1.0f);
}